// Round 16
// baseline (688.146 us; speedup 1.0000x reference)
//
#include <hip/hip_runtime.h>
#include <math.h>

// Problem constants (from setup_inputs)
#define N_NODES 4096
#define BATCH   32
#define D_EMB   10
#define CIN     2
#define COUT    64
#define CI      66          // CIN + COUT
#define KSUP    3
#define NCOLS   2112        // BATCH * CI
#define NPAD    2176        // NCOLS padded (n-layout row stride)
#define LDT     4096        // t-layout row stride (m contiguous)

// MFMA-transform constants (R15 ki-relayout, proven)
#define KSEC    72          // per-support section stride (halves)
#define KI_REAL 216         // 3*KSEC
#define KILD    232         // LDS row stride (conflict-safe)
#define OCH     (32 * KILD)
#define WROW_G  (128 * KILD)
#define WROW_U  (64 * KILD)
#define WGT2_R  (WROW_G + WROW_U)

typedef _Float16 half_t;
typedef __attribute__((ext_vector_type(8))) _Float16 f16x8;
typedef __attribute__((ext_vector_type(4))) _Float16 f16x4;
typedef __attribute__((ext_vector_type(2))) _Float16 f16x2;
typedef __attribute__((ext_vector_type(4))) float f32x4;

union u32h2 { unsigned u; f16x2 h; };

struct __attribute__((packed, aligned(4))) uint4_u4 { uint4 v; };
__device__ __forceinline__ f16x8 loadu8h(const half_t* p) {
  union { uint4 u; f16x8 h; } r;
  r.u = ((const uint4_u4*)p)->v;
  return r.h;
}

__device__ __forceinline__ float fast_sigmoid(float x) { return 1.f / (1.f + __expf(-x)); }
__device__ __forceinline__ float fast_tanh(float x) { return 1.f - 2.f / (__expf(2.f * x) + 1.f); }

__device__ __forceinline__ void gld_lds16(const half_t* g, half_t* l) {
  __builtin_amdgcn_global_load_lds(
      (const __attribute__((address_space(1))) void*)g,
      (__attribute__((address_space(3))) void*)l, 16, 0, 0);
}

// ---------------------------------------------------------------------------
// P[n,m] = softmax_m(relu(E[n,:].E[m,:])) stored directly as fp16.
// R19: register-cached dot products (single E.E pass).
// ---------------------------------------------------------------------------
__global__ __launch_bounds__(256) void k_softmax_p(const float* __restrict__ E,
                                                   half_t* __restrict__ Pb) {
  const int n = blockIdx.x;
  const int tid = threadIdx.x;
  __shared__ float En[D_EMB];
  __shared__ float ms[256], ss[256];
  if (tid < D_EMB) En[tid] = E[n * D_EMB + tid];
  __syncthreads();
  float en[D_EMB];
#pragma unroll
  for (int d = 0; d < D_EMB; ++d) en[d] = En[d];

  float val[16];
  float m = -1e30f, s = 0.f;
#pragma unroll
  for (int it = 0; it < 16; ++it) {
    const int c = tid + it * 256;
    const float* Ec = E + c * D_EMB;
    float v = 0.f;
#pragma unroll
    for (int d = 0; d < D_EMB; ++d) v += en[d] * Ec[d];
    v = fmaxf(v, 0.f);
    val[it] = v;
    if (v > m) { s *= __expf(m - v); m = v; }
    s += __expf(v - m);
  }
  ms[tid] = m; ss[tid] = s;
  __syncthreads();
  for (int off = 128; off > 0; off >>= 1) {
    if (tid < off) {
      float m2 = ms[tid + off], s2 = ss[tid + off];
      float m1 = ms[tid], s1 = ss[tid];
      float mm = fmaxf(m1, m2);
      ms[tid] = mm;
      ss[tid] = s1 * __expf(m1 - mm) + s2 * __expf(m2 - mm);
    }
    __syncthreads();
  }
  const float M = ms[0];
  const float inv = 1.f / ss[0];
  half_t* Pr = Pb + (size_t)n * N_NODES;
#pragma unroll
  for (int it = 0; it < 16; ++it)
    Pr[tid + it * 256] = (half_t)(__expf(val[it] - M) * inv);
}

// ---------------------------------------------------------------------------
// R23: tile-based build (verified R11). Vn coalesced; Vt via LDS transpose.
// ---------------------------------------------------------------------------
__global__ __launch_bounds__(256) void k_build_v0(const float* __restrict__ X,
                                                  const float* __restrict__ H,
                                                  half_t* __restrict__ Vt,
                                                  half_t* __restrict__ Vn,
                                                  half_t* __restrict__ Cbn) {
  __shared__ half_t T[64][69];
  const int tid = threadIdx.x;
  const int ct = blockIdx.x * 64;   // col base (0..2048)
  const int mt = blockIdx.y * 64;   // node base
  const int r0 = tid >> 4;
  const int c4 = (tid & 15) * 4;
#pragma unroll
  for (int it = 0; it < 4; ++it) {
    const int r = r0 + it * 16;
    const int m = mt + r;
    half_t hv[4];
#pragma unroll
    for (int j = 0; j < 4; ++j) {
      const int col = ct + c4 + j;
      const int b = col / CI;
      const int c = col - b * CI;
      float v;
      if (c < CIN) v = X[((size_t)b * N_NODES + m) * CIN + c];
      else         v = H[((size_t)b * N_NODES + m) * COUT + (c - CIN)];
      hv[j] = (half_t)v;
      T[r][c4 + j] = hv[j];
      if (c < CIN) Cbn[(size_t)m * NPAD + col] = hv[j];
    }
    f16x4 v4 = {hv[0], hv[1], hv[2], hv[3]};
    *(f16x4*)&Vn[(size_t)m * NPAD + ct + c4] = v4;
  }
  __syncthreads();
#pragma unroll
  for (int it = 0; it < 4; ++it) {
    const int cc = r0 + it * 16;     // col within tile
    const int m4 = c4;               // node within tile
    f16x4 v = {T[m4 + 0][cc], T[m4 + 1][cc], T[m4 + 2][cc], T[m4 + 3][cc]};
    *(f16x4*)&Vt[(size_t)(ct + cc) * LDT + mt + m4] = v;
  }
}

// ---------------------------------------------------------------------------
// R27 fp16 MFMA NT-GEMM: R24 structure with RING-3 (48KB LDS) -> 3 blocks/CU
// resident. Occupancy arithmetic on R15's counters: 28.7% measured vs 50%
// all-resident => ~45% of GEMM time was the 32-block tail phase (224 CUs
// idle). At 48KB all 544 blocks are resident from t=0 (32 CUs carry 3, 224
// carry 2) -> tail overlaps the main phase. Depth-2 counted-vmcnt (R14-proven
// pattern, 2 loads/stage -> steady vmcnt(2), tail 2/0). Everything else
// identical to R24: 128x128 tile, 8 waves (64x32, acc[4][2]), R13 swizzle,
// XCD-bijective swizzle. VGPR 52 <= 85 supports 6 waves/SIMD.
// ---------------------------------------------------------------------------
__device__ __forceinline__ void gemm_compute_tile(const half_t* __restrict__ Lb,
                                                  int wm, int wn, int fofs,
                                                  f32x4 (&acc)[4][2]) {
  f16x8 a[4], b[2];
#pragma unroll
  for (int i = 0; i < 4; ++i)
    a[i] = *(const f16x8*)&Lb[((wm >> 4) + i) * 512 + fofs];
#pragma unroll
  for (int j = 0; j < 2; ++j)
    b[j] = *(const f16x8*)&Lb[4096 + ((wn >> 4) + j) * 512 + fofs];
  __builtin_amdgcn_s_setprio(1);
#pragma unroll
  for (int i = 0; i < 4; ++i)
#pragma unroll
    for (int j = 0; j < 2; ++j)
      acc[i][j] = __builtin_amdgcn_mfma_f32_16x16x32_f16(a[i], b[j], acc[i][j], 0, 0, 0);
  __builtin_amdgcn_s_setprio(0);
}

__global__ __launch_bounds__(512) void k_gemm_f16(const half_t* __restrict__ A,
                                                  const half_t* __restrict__ Bt,
                                                  half_t* __restrict__ Cn,
                                                  half_t* __restrict__ Ct) {
  __shared__ half_t LB[3][8192];   // 48 KB: 3 buffers (depth-2 ring)
  const int tid = threadIdx.x;
  const int lane = tid & 63;
  const int wave = tid >> 6;       // 0..7

  int flat = blockIdx.y * 17 + blockIdx.x;
  flat = (flat & 7) * 68 + (flat >> 3);
  const int bx = flat % 17;
  const int by = flat / 17;

  const int wm = (wave >> 2) * 64;   // 2 waves across M
  const int wn = (wave & 3) * 32;    // 4 waves across N
  const int rb = by * 128;
  const int cb = bx * 128;

  // swizzled staging (R13): wave w stages A-granule w + B-granule w
  const int srow = lane >> 2;
  const int skg = (((lane & 3) + ((lane >> 3) & 3)) & 3) * 8;
  const half_t* ga0 = A + (size_t)(rb + wave * 16 + srow) * N_NODES + skg;
  const half_t* gb0 = Bt + (size_t)(cb + wave * 16 + srow) * LDT + skg;
  const int lA0 = wave * 512;
  const int lB0 = 4096 + wave * 512;

  const int fr = lane & 15;
  const int fg = lane >> 4;
  const int fofs = (4 * fr + ((fg - (fr >> 1)) & 3)) * 8;

  f32x4 acc[4][2] = {};

#define STAGE_T(buf, kk) do { half_t* Lp = LB[(buf)]; \
    gld_lds16(ga0 + (kk), Lp + lA0); gld_lds16(gb0 + (kk), Lp + lB0); } while (0)

  // prologue: stages 0,1 in flight (4 outstanding VMEM ops/wave)
  STAGE_T(0, 0);
  STAGE_T(1, 32);

  // 128 K-phases; loop covers 0..125 (42 iters x 3 for static buf indices).
  // Invariant at sub-iter for phase T: outstanding stages {T, T+1} (4 loads);
  // vmcnt(2) -> stage T complete. STAGE(T+2) writes buf[(T+2)%3] =
  // buf[(T-1)%3], read by compute(T-1); barrier reached only after it (WAR ok).
  for (int t = 0; t < 126; t += 3) {
    asm volatile("s_waitcnt vmcnt(2)\n\ts_barrier" ::: "memory");
    STAGE_T(2, (t + 2) * 32);
    gemm_compute_tile(LB[0], wm, wn, fofs, acc);

    asm volatile("s_waitcnt vmcnt(2)\n\ts_barrier" ::: "memory");
    STAGE_T(0, (t + 3) * 32);
    gemm_compute_tile(LB[1], wm, wn, fofs, acc);

    asm volatile("s_waitcnt vmcnt(2)\n\ts_barrier" ::: "memory");
    STAGE_T(1, (t + 4) * 32);
    gemm_compute_tile(LB[2], wm, wn, fofs, acc);
  }
  // tail: phases 126 (buf 0) and 127 (buf 1); outstanding {126,127}
  asm volatile("s_waitcnt vmcnt(2)\n\ts_barrier" ::: "memory");
  gemm_compute_tile(LB[0], wm, wn, fofs, acc);
  asm volatile("s_waitcnt vmcnt(0)\n\ts_barrier" ::: "memory");
  gemm_compute_tile(LB[1], wm, wn, fofs, acc);
#undef STAGE_T

  const int en = lane & 15;
  const int em = (lane >> 4) * 4;
#pragma unroll
  for (int i = 0; i < 4; ++i) {
#pragma unroll
    for (int j = 0; j < 2; ++j) {
      const int m0 = rb + wm + i * 16 + em;
      const int n = cb + wn + j * 16 + en;
      half_t h0 = (half_t)acc[i][j][0];
      half_t h1 = (half_t)acc[i][j][1];
      half_t h2 = (half_t)acc[i][j][2];
      half_t h3 = (half_t)acc[i][j][3];
      if (Ct) {
        f16x4 t4 = {h0, h1, h2, h3};
        *(f16x4*)&Ct[(size_t)n * LDT + m0] = t4;
      }
      Cn[(size_t)(m0 + 0) * NPAD + n] = h0;
      Cn[(size_t)(m0 + 1) * NPAD + n] = h1;
      Cn[(size_t)(m0 + 2) * NPAD + n] = h2;
      Cn[(size_t)(m0 + 3) * NPAD + n] = h3;
    }
  }
}

// ---------------------------------------------------------------------------
// Coalesced transpose n-layout -> t-layout (64x64 LDS tiles).
// ---------------------------------------------------------------------------
__global__ __launch_bounds__(256) void k_tr(const half_t* __restrict__ Cbn,
                                            half_t* __restrict__ Ct) {
  __shared__ half_t T[64][69];
  const int tid = threadIdx.x;
  const int cb = blockIdx.x * 64;
  const int mb = blockIdx.y * 64;
  const int c4 = (tid & 15) * 4;
  const int r0 = tid >> 4;
#pragma unroll
  for (int it = 0; it < 4; ++it) {
    const int r = r0 + it * 16;
    f16x4 v = *(const f16x4*)&Cbn[(size_t)(mb + r) * NPAD + cb + c4];
    T[r][c4 + 0] = v[0];
    T[r][c4 + 1] = v[1];
    T[r][c4 + 2] = v[2];
    T[r][c4 + 3] = v[3];
  }
  __syncthreads();
#pragma unroll
  for (int it = 0; it < 4; ++it) {
    const int c2 = r0 + it * 16;
    const int m4 = c4;
    f16x4 v = {T[m4 + 0][c2], T[m4 + 1][c2], T[m4 + 2][c2], T[m4 + 3][c2]};
    *(f16x4*)&Ct[(size_t)(cb + c2) * LDT + mb + m4] = v;
  }
}

// ---------------------------------------------------------------------------
// WT2: d-pair-packed fp16 pool, L2-resident (R15 ki = k*KSEC + i layout).
// ---------------------------------------------------------------------------
__global__ __launch_bounds__(256) void k_wgt2(const float* __restrict__ Wg,
                                              const float* __restrict__ Wu,
                                              unsigned* __restrict__ WT2) {
  const int r = blockIdx.x * 256 + threadIdx.x;
  if (r >= WGT2_R) return;
  const float* pool;
  int o, ki, ostr;
  if (r < WROW_G) { o = r / KILD; ki = r % KILD; pool = Wg; ostr = 128; }
  else { int r2 = r - WROW_G; o = r2 / KILD; ki = r2 % KILD; pool = Wu; ostr = 64; }
  const int k = ki / KSEC;
  const int i = ki - k * KSEC;
#pragma unroll
  for (int dp = 0; dp < 5; ++dp) {
    u32h2 v; v.h = f16x2{(half_t)0.f, (half_t)0.f};
    if (ki < KI_REAL && i < CI) {
      v.h[0] = (half_t)pool[(((size_t)(2 * dp) * KSUP + k) * CI + i) * ostr + o];
      v.h[1] = (half_t)pool[(((size_t)(2 * dp + 1) * KSUP + k) * CI + i) * ostr + o];
    }
    WT2[(size_t)dp * WGT2_R + r] = v.u;
  }
}

// ---------------------------------------------------------------------------
// R22: stage xg for FOUR nodes into LDS (512-thread blocks).
// ---------------------------------------------------------------------------
__device__ __forceinline__ void stage_xg4(const half_t* __restrict__ v0b,
                                          const half_t* __restrict__ g1b,
                                          const half_t* __restrict__ g2b,
                                          half_t* __restrict__ xg,  // [4*OCH]
                                          int n0, int tid, int nthr) {
  for (int w = tid; w < 4 * 288; w += nthr) {
    const int nd = w / 288;
    const int rem = w - nd * 288;
    const int b = rem / 9;
    const int oct = rem - b * 9;
    const size_t src = (size_t)(n0 + nd) * NPAD + b * CI;
    half_t* row = xg + nd * OCH + b * KILD;
    const half_t* pv = v0b + src;
    const half_t* pg1 = g1b + src;
    const half_t* pg2 = g2b + src;
    if (oct < 8) {
      const f16x8 v0 = loadu8h(pv + oct * 8);
      const f16x8 g1 = loadu8h(pg1 + oct * 8);
      const f16x8 g2 = loadu8h(pg2 + oct * 8);
      const f16x8 x2 = g2 + g2 - v0;
      *(f16x8*)&row[oct * 8] = v0;
      *(f16x8*)&row[KSEC + oct * 8] = g1;
      *(f16x8*)&row[2 * KSEC + oct * 8] = x2;
    } else {
      u32h2 tv, tg1, tg2;
      tv.u = *(const unsigned*)(pv + 64);
      tg1.u = *(const unsigned*)(pg1 + 64);
      tg2.u = *(const unsigned*)(pg2 + 64);
      f16x8 v0 = {}, g1 = {}, x2 = {};
      v0[0] = tv.h[0]; v0[1] = tv.h[1];
      g1[0] = tg1.h[0]; g1[1] = tg1.h[1];
      x2[0] = tg2.h[0] + tg2.h[0] - tv.h[0];
      x2[1] = tg2.h[1] + tg2.h[1] - tv.h[1];
      *(f16x8*)&row[64] = v0;
      *(f16x8*)&row[KSEC + 64] = g1;
      *(f16x8*)&row[2 * KSEC + 64] = x2;
    }
  }
  // zero row pad [216, 232) for all 4 nodes
  for (int w = tid; w < 4 * 64; w += nthr) {
    const int nd = w >> 6;
    const int z = w & 63;
    const f16x8 zz = {};
    *(f16x8*)&xg[nd * OCH + (z >> 1) * KILD + KI_REAL + (z & 1) * 8] = zz;
  }
}

// ---------------------------------------------------------------------------
// R22 gate transform: block = 4 nodes, 512 threads, ~60KB LDS (verified R12).
// ---------------------------------------------------------------------------
__global__ __launch_bounds__(512) void k_gate_t(const half_t* __restrict__ Vn,
                                                const half_t* __restrict__ G1n,
                                                const half_t* __restrict__ G2n,
                                                const unsigned* __restrict__ WT2,
                                                const float* __restrict__ E,
                                                const float* __restrict__ bg,
                                                const float* __restrict__ H,
                                                half_t* __restrict__ Cbn,
                                                half_t* __restrict__ Rb) {
  const int n0 = blockIdx.x * 4;
  const int tid = threadIdx.x;
  const int lane = tid & 63;
  const int wave = tid >> 6;
  __shared__ half_t S[4 * OCH];      // xg staging, then reused as Wl[4]
  __shared__ float biasl[4][128];

  f16x2 e2p[4][5];
#pragma unroll
  for (int nd = 0; nd < 4; ++nd)
#pragma unroll
    for (int dp = 0; dp < 5; ++dp) {
      e2p[nd][dp][0] = (half_t)E[(n0 + nd) * D_EMB + 2 * dp];
      e2p[nd][dp][1] = (half_t)E[(n0 + nd) * D_EMB + 2 * dp + 1];
    }

  {
    const int nn = tid >> 7;           // 0..3
    const int o = tid & 127;
    float s = 0.f;
#pragma unroll
    for (int d = 0; d < D_EMB; ++d) s += E[(n0 + nn) * D_EMB + d] * bg[d * 128 + o];
    biasl[nn][o] = s;
  }
  stage_xg4(Vn, G1n, G2n, S, n0, tid, 512);
  __syncthreads();

  const int fr = lane & 15;
  const int fk = (lane >> 4) * 8;
  const int en = lane & 15;
  const int em = (lane >> 4) * 4;
  const int node = wave & 3;
  const int bh = wave >> 2;            // batch half
  const int nn = n0 + node;

  // hoist A-fragments (p-invariant) into registers: 7 x f16x8 = 28 VGPRs
  f16x8 af[7];
#pragma unroll
  for (int ks = 0; ks < 7; ++ks)
    af[ks] = *(const f16x8*)&S[node * OCH + (bh * 16 + fr) * KILD + ks * 32 + fk];
  __syncthreads();   // all af reads done before S is overwritten as Wl

#pragma unroll
  for (int p = 0; p < 4; ++p) {
    if (p > 0) __syncthreads();        // prev MFMA reads done before Wl overwrite
    for (int base = tid * 8; base < OCH; base += 4096) {
      float a[4][8] = {};
#pragma unroll
      for (int dp = 0; dp < 5; ++dp) {
        const unsigned* wrow = WT2 + (size_t)dp * WGT2_R + p * OCH + base;
        uint4 wa = *(const uint4*)wrow;
        uint4 wb = *(const uint4*)(wrow + 4);
        u32h2 c0, c1, c2, c3;
        c0.u = wa.x; c1.u = wa.y; c2.u = wa.z; c3.u = wa.w;
#pragma unroll
        for (int nd = 0; nd < 4; ++nd) {
          a[nd][0] = __builtin_amdgcn_fdot2(c0.h, e2p[nd][dp], a[nd][0], false);
          a[nd][1] = __builtin_amdgcn_fdot2(c1.h, e2p[nd][dp], a[nd][1], false);
          a[nd][2] = __builtin_amdgcn_fdot2(c2.h, e2p[nd][dp], a[nd][2], false);
          a[nd][3] = __builtin_amdgcn_fdot2(c3.h, e2p[nd][dp], a[nd][3], false);
        }
        c0.u = wb.x; c1.u = wb.y; c2.u = wb.z; c3.u = wb.w;
#pragma unroll
        for (int nd = 0; nd < 4; ++nd) {
          a[nd][4] = __builtin_amdgcn_fdot2(c0.h, e2p[nd][dp], a[nd][4], false);
          a[nd][5] = __builtin_amdgcn_fdot2(c1.h, e2p[nd][dp], a[nd][5], false);
          a[nd][6] = __builtin_amdgcn_fdot2(c2.h, e2p[nd][dp], a[nd][6], false);
          a[nd][7] = __builtin_amdgcn_fdot2(c3.h, e2p[nd][dp], a[nd][7], false);
        }
      }
#pragma unroll
      for (int nd = 0; nd < 4; ++nd) {
        f16x8 w0;
#pragma unroll
        for (int e = 0; e < 8; ++e) w0[e] = (half_t)a[nd][e];
        *(f16x8*)&S[nd * OCH + base] = w0;
      }
    }
    __syncthreads();

    f32x4 acc2[2] = {};
#pragma unroll
    for (int ks = 0; ks < 7; ++ks) {
#pragma unroll
      for (int ot = 0; ot < 2; ++ot) {
        const f16x8 b0 = *(const f16x8*)&S[node * OCH + (ot * 16 + fr) * KILD + ks * 32 + fk];
        acc2[ot] = __builtin_amdgcn_mfma_f32_16x16x32_f16(af[ks], b0, acc2[ot], 0, 0, 0);
      }
    }
#pragma unroll
    for (int ot = 0; ot < 2; ++ot) {
      const int o_g = p * 32 + ot * 16 + en;
      const float bo = biasl[node][o_g];
#pragma unroll
      for (int r = 0; r < 4; ++r) {
        const int b = bh * 16 + em + r;
        const float s = fast_sigmoid(acc2[ot][r] + bo);
        if (p < 2) {
          const float hv = H[((size_t)b * N_NODES + nn) * COUT + o_g];
          const half_t z = (half_t)(s * hv);
          Cbn[(size_t)nn * NPAD + b * CI + CIN + o_g] = z;
        } else {
          Rb[(size_t)nn * 2048 + b * COUT + (o_g - 64)] = (half_t)s;
        }
      }
    }
  }
}

// ---------------------------------------------------------------------------
// R22 update transform: block = 4 nodes, 512 threads (verified R12).
// ---------------------------------------------------------------------------
__global__ __launch_bounds__(512) void k_update_t(const half_t* __restrict__ Cbn,
                                                  const half_t* __restrict__ G1n,
                                                  const half_t* __restrict__ G2n,
                                                  const unsigned* __restrict__ WT2,
                                                  const float* __restrict__ E,
                                                  const float* __restrict__ bu,
                                                  const float* __restrict__ H,
                                                  const half_t* __restrict__ Rb,
                                                  float* __restrict__ Out) {
  const int n0 = blockIdx.x * 4;
  const int tid = threadIdx.x;
  const int lane = tid & 63;
  const int wave = tid >> 6;
  __shared__ half_t S[4 * OCH];
  __shared__ float biasl[4][64];

  f16x2 e2p[4][5];
#pragma unroll
  for (int nd = 0; nd < 4; ++nd)
#pragma unroll
    for (int dp = 0; dp < 5; ++dp) {
      e2p[nd][dp][0] = (half_t)E[(n0 + nd) * D_EMB + 2 * dp];
      e2p[nd][dp][1] = (half_t)E[(n0 + nd) * D_EMB + 2 * dp + 1];
    }

  if (tid < 256) {
    const int nn = tid >> 6;
    const int o = tid & 63;
    float s = 0.f;
#pragma unroll
    for (int d = 0; d < D_EMB; ++d) s += E[(n0 + nn) * D_EMB + d] * bu[d * COUT + o];
    biasl[nn][o] = s;
  }
  stage_xg4(Cbn, G1n, G2n, S, n0, tid, 512);
  __syncthreads();

  const int fr = lane & 15;
  const int fk = (lane >> 4) * 8;
  const int en = lane & 15;
  const int em = (lane >> 4) * 4;
  const int node = wave & 3;
  const int bh = wave >> 2;
  const int nn = n0 + node;

  f16x8 af[7];
#pragma unroll
  for (int ks = 0; ks < 7; ++ks)
    af[ks] = *(const f16x8*)&S[node * OCH + (bh * 16 + fr) * KILD + ks * 32 + fk];
  __syncthreads();

#pragma unroll
  for (int p = 0; p < 2; ++p) {
    if (p > 0) __syncthreads();
    for (int base = tid * 8; base < OCH; base += 4096) {
      float a[4][8] = {};
#pragma unroll
      for (int dp = 0; dp < 5; ++dp) {
        const unsigned* wrow = WT2 + (size_t)dp * WGT2_R + WROW_G + p * OCH + base;
        uint4 wa = *(const uint4*)wrow;
        uint4 wb = *(const uint4*)(wrow + 4);
        u32h2 c0, c1, c2, c3;
        c0.u = wa.x; c1.u = wa.y; c2.u = wa.z; c3.u = wa.w;
#pragma unroll
        for (int nd = 0; nd < 4; ++nd) {
          a[nd][0] = __builtin_amdgcn_fdot2(c0.h, e2p[nd][dp], a[nd][0], false);
          a[nd][1] = __builtin_amdgcn_fdot2(c1.h, e2p[nd][dp], a[nd][1], false);
          a[nd][2] = __builtin_amdgcn_fdot2(c2.h, e2p[nd][dp], a[nd][2], false);
          a[nd][3] = __builtin_amdgcn_fdot2(c3.h, e2p[nd][dp], a[nd][3], false);
        }
        c0.u = wb.x; c1.u = wb.y; c2.u = wb.z; c3.u = wb.w;
#pragma unroll
        for (int nd = 0; nd < 4; ++nd) {
          a[nd][4] = __builtin_amdgcn_fdot2(c0.h, e2p[nd][dp], a[nd][4], false);
          a[nd][5] = __builtin_amdgcn_fdot2(c1.h, e2p[nd][dp], a[nd][5], false);
          a[nd][6] = __builtin_amdgcn_fdot2(c2.h, e2p[nd][dp], a[nd][6], false);
          a[nd][7] = __builtin_amdgcn_fdot2(c3.h, e2p[nd][dp], a[nd][7], false);
        }
      }
#pragma unroll
      for (int nd = 0; nd < 4; ++nd) {
        f16x8 w0;
#pragma unroll
        for (int e = 0; e < 8; ++e) w0[e] = (half_t)a[nd][e];
        *(f16x8*)&S[nd * OCH + base] = w0;
      }
    }
    __syncthreads();

    f32x4 acc2[2] = {};
#pragma unroll
    for (int ks = 0; ks < 7; ++ks) {
#pragma unroll
      for (int ot = 0; ot < 2; ++ot) {
        const f16x8 b0 = *(const f16x8*)&S[node * OCH + (ot * 16 + fr) * KILD + ks * 32 + fk];
        acc2[ot] = __builtin_amdgcn_mfma_f32_16x16x32_f16(af[ks], b0, acc2[ot], 0, 0, 0);
      }
    }
#pragma unroll
    for (int ot = 0; ot < 2; ++ot) {
      const int o = p * 32 + ot * 16 + en;
      const float bo = biasl[node][o];
#pragma unroll
      for (int r = 0; r < 4; ++r) {
        const int b = bh * 16 + em + r;
        const float hc = fast_tanh(acc2[ot][r] + bo);
        const float hv = H[((size_t)b * N_NODES + nn) * COUT + o];
        const float rr = (float)Rb[(size_t)nn * 2048 + b * COUT + o];
        Out[((size_t)b * N_NODES + nn) * COUT + o] = rr * hv + (1.f - rr) * hc;
      }
    }
  }
}

// ---------------------------------------------------------------------------
extern "C" void kernel_launch(void* const* d_in, const int* in_sizes, int n_in,
                              void* d_out, int out_size, void* d_ws, size_t ws_size,
                              hipStream_t stream) {
  const float* X  = (const float*)d_in[0];
  const float* H  = (const float*)d_in[1];
  const float* E  = (const float*)d_in[2];
  const float* Wg = (const float*)d_in[3];
  const float* bg = (const float*)d_in[4];
  const float* Wu = (const float*)d_in[5];
  const float* bu = (const float*)d_in[6];
  float* out = (float*)d_out;

  const size_t SZ_P = (size_t)N_NODES * N_NODES;
  const size_t SZ_M = (size_t)NPAD * LDT;
  half_t* Pb  = (half_t*)d_ws;
  half_t* Vt  = Pb + SZ_P;
  half_t* Vn  = Vt + SZ_M;
  half_t* G1t = Vn + SZ_M;
  half_t* G1n = G1t + SZ_M;
  half_t* G2n = G1n + SZ_M;
  half_t* Cbt = G2n + SZ_M;
  half_t* Cbn = Cbt + SZ_M;
  half_t* Rb  = Cbn + SZ_M;
  unsigned* WT2 = (unsigned*)(Rb + (size_t)BATCH * N_NODES * COUT);

  const dim3 gg(17, 32);       // full-K GEMM grid
  const dim3 gt(33, 64);       // 64x64 tile grid over 2112 cols x 4096 nodes

  // 1. adjacency + inputs + packed pool
  k_softmax_p<<<N_NODES, 256, 0, stream>>>(E, Pb);
  k_build_v0<<<gt, 256, 0, stream>>>(X, H, Vt, Vn, Cbn);
  k_wgt2<<<(WGT2_R + 255) / 256, 256, 0, stream>>>(Wg, Wu, WT2);

  // 2. gate propagation + transform
  k_gemm_f16<<<gg, 512, 0, stream>>>(Pb, Vt, G1n, G1t);
  k_gemm_f16<<<gg, 512, 0, stream>>>(Pb, G1t, G2n, nullptr);
  k_gate_t<<<N_NODES / 4, 512, 0, stream>>>(Vn, G1n, G2n, WT2, E, bg, H, Cbn, Rb);
  k_tr<<<gt, 256, 0, stream>>>(Cbn, Cbt);

  // 3. update propagation + transform + output
  k_gemm_f16<<<gg, 512, 0, stream>>>(Pb, Cbt, G1n, G1t);
  k_gemm_f16<<<gg, 512, 0, stream>>>(Pb, G1t, G2n, nullptr);
  k_update_t<<<N_NODES / 4, 512, 0, stream>>>(Cbn, G1n, G2n, WT2, E, bu, H, Rb, out);
}

// Round 17
// 670.304 us; speedup vs baseline: 1.0266x; 1.0266x over previous
//
#include <hip/hip_runtime.h>
#include <math.h>

// Problem constants (from setup_inputs)
#define N_NODES 4096
#define BATCH   32
#define D_EMB   10
#define CIN     2
#define COUT    64
#define CI      66          // CIN + COUT
#define KSUP    3
#define NCOLS   2112        // BATCH * CI
#define NPAD    2176        // NCOLS padded (n-layout row stride)
#define LDT     4096        // t-layout row stride (m contiguous)

// MFMA-transform constants (R15 ki-relayout, proven)
#define KSEC    72          // per-support section stride (halves)
#define KI_REAL 216         // 3*KSEC
#define KILD    232         // LDS row stride (conflict-safe)
#define OCH     (32 * KILD)
#define WROW_G  (128 * KILD)
#define WROW_U  (64 * KILD)
#define WGT2_R  (WROW_G + WROW_U)

typedef _Float16 half_t;
typedef __attribute__((ext_vector_type(8))) _Float16 f16x8;
typedef __attribute__((ext_vector_type(4))) _Float16 f16x4;
typedef __attribute__((ext_vector_type(2))) _Float16 f16x2;
typedef __attribute__((ext_vector_type(4))) float f32x4;

union u32h2 { unsigned u; f16x2 h; };

struct __attribute__((packed, aligned(4))) uint4_u4 { uint4 v; };
__device__ __forceinline__ f16x8 loadu8h(const half_t* p) {
  union { uint4 u; f16x8 h; } r;
  r.u = ((const uint4_u4*)p)->v;
  return r.h;
}

__device__ __forceinline__ float fast_sigmoid(float x) { return 1.f / (1.f + __expf(-x)); }
__device__ __forceinline__ float fast_tanh(float x) { return 1.f - 2.f / (__expf(2.f * x) + 1.f); }

__device__ __forceinline__ void gld_lds16(const half_t* g, half_t* l) {
  __builtin_amdgcn_global_load_lds(
      (const __attribute__((address_space(1))) void*)g,
      (__attribute__((address_space(3))) void*)l, 16, 0, 0);
}

// ---------------------------------------------------------------------------
// P[n,m] = softmax_m(relu(E[n,:].E[m,:])) stored directly as fp16.
// R19: register-cached dot products (single E.E pass).
// ---------------------------------------------------------------------------
__global__ __launch_bounds__(256) void k_softmax_p(const float* __restrict__ E,
                                                   half_t* __restrict__ Pb) {
  const int n = blockIdx.x;
  const int tid = threadIdx.x;
  __shared__ float En[D_EMB];
  __shared__ float ms[256], ss[256];
  if (tid < D_EMB) En[tid] = E[n * D_EMB + tid];
  __syncthreads();
  float en[D_EMB];
#pragma unroll
  for (int d = 0; d < D_EMB; ++d) en[d] = En[d];

  float val[16];
  float m = -1e30f, s = 0.f;
#pragma unroll
  for (int it = 0; it < 16; ++it) {
    const int c = tid + it * 256;
    const float* Ec = E + c * D_EMB;
    float v = 0.f;
#pragma unroll
    for (int d = 0; d < D_EMB; ++d) v += en[d] * Ec[d];
    v = fmaxf(v, 0.f);
    val[it] = v;
    if (v > m) { s *= __expf(m - v); m = v; }
    s += __expf(v - m);
  }
  ms[tid] = m; ss[tid] = s;
  __syncthreads();
  for (int off = 128; off > 0; off >>= 1) {
    if (tid < off) {
      float m2 = ms[tid + off], s2 = ss[tid + off];
      float m1 = ms[tid], s1 = ss[tid];
      float mm = fmaxf(m1, m2);
      ms[tid] = mm;
      ss[tid] = s1 * __expf(m1 - mm) + s2 * __expf(m2 - mm);
    }
    __syncthreads();
  }
  const float M = ms[0];
  const float inv = 1.f / ss[0];
  half_t* Pr = Pb + (size_t)n * N_NODES;
#pragma unroll
  for (int it = 0; it < 16; ++it)
    Pr[tid + it * 256] = (half_t)(__expf(val[it] - M) * inv);
}

// ---------------------------------------------------------------------------
// R23: tile-based build (verified R11). Vn coalesced; Vt via LDS transpose.
// ---------------------------------------------------------------------------
__global__ __launch_bounds__(256) void k_build_v0(const float* __restrict__ X,
                                                  const float* __restrict__ H,
                                                  half_t* __restrict__ Vt,
                                                  half_t* __restrict__ Vn,
                                                  half_t* __restrict__ Cbn) {
  __shared__ half_t T[64][69];
  const int tid = threadIdx.x;
  const int ct = blockIdx.x * 64;   // col base (0..2048)
  const int mt = blockIdx.y * 64;   // node base
  const int r0 = tid >> 4;
  const int c4 = (tid & 15) * 4;
#pragma unroll
  for (int it = 0; it < 4; ++it) {
    const int r = r0 + it * 16;
    const int m = mt + r;
    half_t hv[4];
#pragma unroll
    for (int j = 0; j < 4; ++j) {
      const int col = ct + c4 + j;
      const int b = col / CI;
      const int c = col - b * CI;
      float v;
      if (c < CIN) v = X[((size_t)b * N_NODES + m) * CIN + c];
      else         v = H[((size_t)b * N_NODES + m) * COUT + (c - CIN)];
      hv[j] = (half_t)v;
      T[r][c4 + j] = hv[j];
      if (c < CIN) Cbn[(size_t)m * NPAD + col] = hv[j];
    }
    f16x4 v4 = {hv[0], hv[1], hv[2], hv[3]};
    *(f16x4*)&Vn[(size_t)m * NPAD + ct + c4] = v4;
  }
  __syncthreads();
#pragma unroll
  for (int it = 0; it < 4; ++it) {
    const int cc = r0 + it * 16;     // col within tile
    const int m4 = c4;               // node within tile
    f16x4 v = {T[m4 + 0][cc], T[m4 + 1][cc], T[m4 + 2][cc], T[m4 + 3][cc]};
    *(f16x4*)&Vt[(size_t)(ct + cc) * LDT + mt + m4] = v;
  }
}

// ---------------------------------------------------------------------------
// R24 fp16 MFMA NT-GEMM (twice-verified at 108.4us): 128x128 tile, 512
// threads / 8 waves (wave = 64x32, acc[4][2]). Depth-3 counted-vmcnt ring-4:
// each wave stages A-granule w + B-granule w (2 gld_lds16/stage, 6
// outstanding, steady vmcnt(4), tail 4/2/0). R13 swizzle + XCD-bijective
// swizzle. GEMM closed after 7 probed axes: tile-shrink (R3), K-split (R4),
// depth (R19), wave-split (R24 +9us), intra-tile K-split (R26 -22us),
// ring-3 residency (R27 -3.4us), XCD swizzle.
// ---------------------------------------------------------------------------
__device__ __forceinline__ void gemm_compute_tile(const half_t* __restrict__ Lb,
                                                  int wm, int wn, int fofs,
                                                  f32x4 (&acc)[4][2]) {
  f16x8 a[4], b[2];
#pragma unroll
  for (int i = 0; i < 4; ++i)
    a[i] = *(const f16x8*)&Lb[((wm >> 4) + i) * 512 + fofs];
#pragma unroll
  for (int j = 0; j < 2; ++j)
    b[j] = *(const f16x8*)&Lb[4096 + ((wn >> 4) + j) * 512 + fofs];
  __builtin_amdgcn_s_setprio(1);
#pragma unroll
  for (int i = 0; i < 4; ++i)
#pragma unroll
    for (int j = 0; j < 2; ++j)
      acc[i][j] = __builtin_amdgcn_mfma_f32_16x16x32_f16(a[i], b[j], acc[i][j], 0, 0, 0);
  __builtin_amdgcn_s_setprio(0);
}

__global__ __launch_bounds__(512) void k_gemm_f16(const half_t* __restrict__ A,
                                                  const half_t* __restrict__ Bt,
                                                  half_t* __restrict__ Cn,
                                                  half_t* __restrict__ Ct) {
  __shared__ half_t LB[4][8192];   // 64 KB: 4 buffers (depth-3 ring)
  const int tid = threadIdx.x;
  const int lane = tid & 63;
  const int wave = tid >> 6;       // 0..7

  int flat = blockIdx.y * 17 + blockIdx.x;
  flat = (flat & 7) * 68 + (flat >> 3);
  const int bx = flat % 17;
  const int by = flat / 17;

  const int wm = (wave >> 2) * 64;   // 2 waves across M
  const int wn = (wave & 3) * 32;    // 4 waves across N
  const int rb = by * 128;
  const int cb = bx * 128;

  // swizzled staging (R13): wave w stages A-granule w + B-granule w
  const int srow = lane >> 2;
  const int skg = (((lane & 3) + ((lane >> 3) & 3)) & 3) * 8;
  const half_t* ga0 = A + (size_t)(rb + wave * 16 + srow) * N_NODES + skg;
  const half_t* gb0 = Bt + (size_t)(cb + wave * 16 + srow) * LDT + skg;
  const int lA0 = wave * 512;
  const int lB0 = 4096 + wave * 512;

  const int fr = lane & 15;
  const int fg = lane >> 4;
  const int fofs = (4 * fr + ((fg - (fr >> 1)) & 3)) * 8;

  f32x4 acc[4][2] = {};

#define STAGE_T(buf, kk) do { half_t* Lp = LB[(buf)]; \
    gld_lds16(ga0 + (kk), Lp + lA0); gld_lds16(gb0 + (kk), Lp + lB0); } while (0)

  // prologue: stages 0,1,2 in flight (6 outstanding VMEM ops/wave)
  STAGE_T(0, 0);
  STAGE_T(1, 32);
  STAGE_T(2, 64);

  for (int t = 0; t < 124; t += 4) {
    asm volatile("s_waitcnt vmcnt(4)\n\ts_barrier" ::: "memory");
    STAGE_T(3, (t + 3) * 32);
    gemm_compute_tile(LB[0], wm, wn, fofs, acc);

    asm volatile("s_waitcnt vmcnt(4)\n\ts_barrier" ::: "memory");
    STAGE_T(0, (t + 4) * 32);
    gemm_compute_tile(LB[1], wm, wn, fofs, acc);

    asm volatile("s_waitcnt vmcnt(4)\n\ts_barrier" ::: "memory");
    STAGE_T(1, (t + 5) * 32);
    gemm_compute_tile(LB[2], wm, wn, fofs, acc);

    asm volatile("s_waitcnt vmcnt(4)\n\ts_barrier" ::: "memory");
    STAGE_T(2, (t + 6) * 32);
    gemm_compute_tile(LB[3], wm, wn, fofs, acc);
  }
  // tail: after loop outstanding = stages 124,125,126 (6 loads)
  asm volatile("s_waitcnt vmcnt(4)\n\ts_barrier" ::: "memory");
  STAGE_T(3, 127 * 32);
  gemm_compute_tile(LB[0], wm, wn, fofs, acc);
  asm volatile("s_waitcnt vmcnt(4)\n\ts_barrier" ::: "memory");
  gemm_compute_tile(LB[1], wm, wn, fofs, acc);
  asm volatile("s_waitcnt vmcnt(2)\n\ts_barrier" ::: "memory");
  gemm_compute_tile(LB[2], wm, wn, fofs, acc);
  asm volatile("s_waitcnt vmcnt(0)\n\ts_barrier" ::: "memory");
  gemm_compute_tile(LB[3], wm, wn, fofs, acc);
#undef STAGE_T

  const int en = lane & 15;
  const int em = (lane >> 4) * 4;
#pragma unroll
  for (int i = 0; i < 4; ++i) {
#pragma unroll
    for (int j = 0; j < 2; ++j) {
      const int m0 = rb + wm + i * 16 + em;
      const int n = cb + wn + j * 16 + en;
      half_t h0 = (half_t)acc[i][j][0];
      half_t h1 = (half_t)acc[i][j][1];
      half_t h2 = (half_t)acc[i][j][2];
      half_t h3 = (half_t)acc[i][j][3];
      if (Ct) {
        f16x4 t4 = {h0, h1, h2, h3};
        *(f16x4*)&Ct[(size_t)n * LDT + m0] = t4;
      }
      Cn[(size_t)(m0 + 0) * NPAD + n] = h0;
      Cn[(size_t)(m0 + 1) * NPAD + n] = h1;
      Cn[(size_t)(m0 + 2) * NPAD + n] = h2;
      Cn[(size_t)(m0 + 3) * NPAD + n] = h3;
    }
  }
}

// ---------------------------------------------------------------------------
// Coalesced transpose n-layout -> t-layout (64x64 LDS tiles).
// ---------------------------------------------------------------------------
__global__ __launch_bounds__(256) void k_tr(const half_t* __restrict__ Cbn,
                                            half_t* __restrict__ Ct) {
  __shared__ half_t T[64][69];
  const int tid = threadIdx.x;
  const int cb = blockIdx.x * 64;
  const int mb = blockIdx.y * 64;
  const int c4 = (tid & 15) * 4;
  const int r0 = tid >> 4;
#pragma unroll
  for (int it = 0; it < 4; ++it) {
    const int r = r0 + it * 16;
    f16x4 v = *(const f16x4*)&Cbn[(size_t)(mb + r) * NPAD + cb + c4];
    T[r][c4 + 0] = v[0];
    T[r][c4 + 1] = v[1];
    T[r][c4 + 2] = v[2];
    T[r][c4 + 3] = v[3];
  }
  __syncthreads();
#pragma unroll
  for (int it = 0; it < 4; ++it) {
    const int c2 = r0 + it * 16;
    const int m4 = c4;
    f16x4 v = {T[m4 + 0][c2], T[m4 + 1][c2], T[m4 + 2][c2], T[m4 + 3][c2]};
    *(f16x4*)&Ct[(size_t)(cb + c2) * LDT + mb + m4] = v;
  }
}

// ---------------------------------------------------------------------------
// WT2: d-pair-packed fp16 pool, L2-resident (R15 ki = k*KSEC + i layout).
// ---------------------------------------------------------------------------
__global__ __launch_bounds__(256) void k_wgt2(const float* __restrict__ Wg,
                                              const float* __restrict__ Wu,
                                              unsigned* __restrict__ WT2) {
  const int r = blockIdx.x * 256 + threadIdx.x;
  if (r >= WGT2_R) return;
  const float* pool;
  int o, ki, ostr;
  if (r < WROW_G) { o = r / KILD; ki = r % KILD; pool = Wg; ostr = 128; }
  else { int r2 = r - WROW_G; o = r2 / KILD; ki = r2 % KILD; pool = Wu; ostr = 64; }
  const int k = ki / KSEC;
  const int i = ki - k * KSEC;
#pragma unroll
  for (int dp = 0; dp < 5; ++dp) {
    u32h2 v; v.h = f16x2{(half_t)0.f, (half_t)0.f};
    if (ki < KI_REAL && i < CI) {
      v.h[0] = (half_t)pool[(((size_t)(2 * dp) * KSUP + k) * CI + i) * ostr + o];
      v.h[1] = (half_t)pool[(((size_t)(2 * dp + 1) * KSUP + k) * CI + i) * ostr + o];
    }
    WT2[(size_t)dp * WGT2_R + r] = v.u;
  }
}

// ---------------------------------------------------------------------------
// R22: stage xg for FOUR nodes into LDS (512-thread blocks).
// ---------------------------------------------------------------------------
__device__ __forceinline__ void stage_xg4(const half_t* __restrict__ v0b,
                                          const half_t* __restrict__ g1b,
                                          const half_t* __restrict__ g2b,
                                          half_t* __restrict__ xg,  // [4*OCH]
                                          int n0, int tid, int nthr) {
  for (int w = tid; w < 4 * 288; w += nthr) {
    const int nd = w / 288;
    const int rem = w - nd * 288;
    const int b = rem / 9;
    const int oct = rem - b * 9;
    const size_t src = (size_t)(n0 + nd) * NPAD + b * CI;
    half_t* row = xg + nd * OCH + b * KILD;
    const half_t* pv = v0b + src;
    const half_t* pg1 = g1b + src;
    const half_t* pg2 = g2b + src;
    if (oct < 8) {
      const f16x8 v0 = loadu8h(pv + oct * 8);
      const f16x8 g1 = loadu8h(pg1 + oct * 8);
      const f16x8 g2 = loadu8h(pg2 + oct * 8);
      const f16x8 x2 = g2 + g2 - v0;
      *(f16x8*)&row[oct * 8] = v0;
      *(f16x8*)&row[KSEC + oct * 8] = g1;
      *(f16x8*)&row[2 * KSEC + oct * 8] = x2;
    } else {
      u32h2 tv, tg1, tg2;
      tv.u = *(const unsigned*)(pv + 64);
      tg1.u = *(const unsigned*)(pg1 + 64);
      tg2.u = *(const unsigned*)(pg2 + 64);
      f16x8 v0 = {}, g1 = {}, x2 = {};
      v0[0] = tv.h[0]; v0[1] = tv.h[1];
      g1[0] = tg1.h[0]; g1[1] = tg1.h[1];
      x2[0] = tg2.h[0] + tg2.h[0] - tv.h[0];
      x2[1] = tg2.h[1] + tg2.h[1] - tv.h[1];
      *(f16x8*)&row[64] = v0;
      *(f16x8*)&row[KSEC + 64] = g1;
      *(f16x8*)&row[2 * KSEC + 64] = x2;
    }
  }
  // zero row pad [216, 232) for all 4 nodes
  for (int w = tid; w < 4 * 64; w += nthr) {
    const int nd = w >> 6;
    const int z = w & 63;
    const f16x8 zz = {};
    *(f16x8*)&xg[nd * OCH + (z >> 1) * KILD + KI_REAL + (z & 1) * 8] = zz;
  }
}

// ---------------------------------------------------------------------------
// R22 gate transform: block = 4 nodes, 512 threads, ~60KB LDS (verified R12).
// ---------------------------------------------------------------------------
__global__ __launch_bounds__(512) void k_gate_t(const half_t* __restrict__ Vn,
                                                const half_t* __restrict__ G1n,
                                                const half_t* __restrict__ G2n,
                                                const unsigned* __restrict__ WT2,
                                                const float* __restrict__ E,
                                                const float* __restrict__ bg,
                                                const float* __restrict__ H,
                                                half_t* __restrict__ Cbn,
                                                half_t* __restrict__ Rb) {
  const int n0 = blockIdx.x * 4;
  const int tid = threadIdx.x;
  const int lane = tid & 63;
  const int wave = tid >> 6;
  __shared__ half_t S[4 * OCH];      // xg staging, then reused as Wl[4]
  __shared__ float biasl[4][128];

  f16x2 e2p[4][5];
#pragma unroll
  for (int nd = 0; nd < 4; ++nd)
#pragma unroll
    for (int dp = 0; dp < 5; ++dp) {
      e2p[nd][dp][0] = (half_t)E[(n0 + nd) * D_EMB + 2 * dp];
      e2p[nd][dp][1] = (half_t)E[(n0 + nd) * D_EMB + 2 * dp + 1];
    }

  {
    const int nn = tid >> 7;           // 0..3
    const int o = tid & 127;
    float s = 0.f;
#pragma unroll
    for (int d = 0; d < D_EMB; ++d) s += E[(n0 + nn) * D_EMB + d] * bg[d * 128 + o];
    biasl[nn][o] = s;
  }
  stage_xg4(Vn, G1n, G2n, S, n0, tid, 512);
  __syncthreads();

  const int fr = lane & 15;
  const int fk = (lane >> 4) * 8;
  const int en = lane & 15;
  const int em = (lane >> 4) * 4;
  const int node = wave & 3;
  const int bh = wave >> 2;            // batch half
  const int nn = n0 + node;

  // hoist A-fragments (p-invariant) into registers: 7 x f16x8 = 28 VGPRs
  f16x8 af[7];
#pragma unroll
  for (int ks = 0; ks < 7; ++ks)
    af[ks] = *(const f16x8*)&S[node * OCH + (bh * 16 + fr) * KILD + ks * 32 + fk];
  __syncthreads();   // all af reads done before S is overwritten as Wl

#pragma unroll
  for (int p = 0; p < 4; ++p) {
    if (p > 0) __syncthreads();        // prev MFMA reads done before Wl overwrite
    for (int base = tid * 8; base < OCH; base += 4096) {
      float a[4][8] = {};
#pragma unroll
      for (int dp = 0; dp < 5; ++dp) {
        const unsigned* wrow = WT2 + (size_t)dp * WGT2_R + p * OCH + base;
        uint4 wa = *(const uint4*)wrow;
        uint4 wb = *(const uint4*)(wrow + 4);
        u32h2 c0, c1, c2, c3;
        c0.u = wa.x; c1.u = wa.y; c2.u = wa.z; c3.u = wa.w;
#pragma unroll
        for (int nd = 0; nd < 4; ++nd) {
          a[nd][0] = __builtin_amdgcn_fdot2(c0.h, e2p[nd][dp], a[nd][0], false);
          a[nd][1] = __builtin_amdgcn_fdot2(c1.h, e2p[nd][dp], a[nd][1], false);
          a[nd][2] = __builtin_amdgcn_fdot2(c2.h, e2p[nd][dp], a[nd][2], false);
          a[nd][3] = __builtin_amdgcn_fdot2(c3.h, e2p[nd][dp], a[nd][3], false);
        }
        c0.u = wb.x; c1.u = wb.y; c2.u = wb.z; c3.u = wb.w;
#pragma unroll
        for (int nd = 0; nd < 4; ++nd) {
          a[nd][4] = __builtin_amdgcn_fdot2(c0.h, e2p[nd][dp], a[nd][4], false);
          a[nd][5] = __builtin_amdgcn_fdot2(c1.h, e2p[nd][dp], a[nd][5], false);
          a[nd][6] = __builtin_amdgcn_fdot2(c2.h, e2p[nd][dp], a[nd][6], false);
          a[nd][7] = __builtin_amdgcn_fdot2(c3.h, e2p[nd][dp], a[nd][7], false);
        }
      }
#pragma unroll
      for (int nd = 0; nd < 4; ++nd) {
        f16x8 w0;
#pragma unroll
        for (int e = 0; e < 8; ++e) w0[e] = (half_t)a[nd][e];
        *(f16x8*)&S[nd * OCH + base] = w0;
      }
    }
    __syncthreads();

    f32x4 acc2[2] = {};
#pragma unroll
    for (int ks = 0; ks < 7; ++ks) {
#pragma unroll
      for (int ot = 0; ot < 2; ++ot) {
        const f16x8 b0 = *(const f16x8*)&S[node * OCH + (ot * 16 + fr) * KILD + ks * 32 + fk];
        acc2[ot] = __builtin_amdgcn_mfma_f32_16x16x32_f16(af[ks], b0, acc2[ot], 0, 0, 0);
      }
    }
#pragma unroll
    for (int ot = 0; ot < 2; ++ot) {
      const int o_g = p * 32 + ot * 16 + en;
      const float bo = biasl[node][o_g];
#pragma unroll
      for (int r = 0; r < 4; ++r) {
        const int b = bh * 16 + em + r;
        const float s = fast_sigmoid(acc2[ot][r] + bo);
        if (p < 2) {
          const float hv = H[((size_t)b * N_NODES + nn) * COUT + o_g];
          const half_t z = (half_t)(s * hv);
          Cbn[(size_t)nn * NPAD + b * CI + CIN + o_g] = z;
        } else {
          Rb[(size_t)nn * 2048 + b * COUT + (o_g - 64)] = (half_t)s;
        }
      }
    }
  }
}

// ---------------------------------------------------------------------------
// R22 update transform: block = 4 nodes, 512 threads (verified R12).
// ---------------------------------------------------------------------------
__global__ __launch_bounds__(512) void k_update_t(const half_t* __restrict__ Cbn,
                                                  const half_t* __restrict__ G1n,
                                                  const half_t* __restrict__ G2n,
                                                  const unsigned* __restrict__ WT2,
                                                  const float* __restrict__ E,
                                                  const float* __restrict__ bu,
                                                  const float* __restrict__ H,
                                                  const half_t* __restrict__ Rb,
                                                  float* __restrict__ Out) {
  const int n0 = blockIdx.x * 4;
  const int tid = threadIdx.x;
  const int lane = tid & 63;
  const int wave = tid >> 6;
  __shared__ half_t S[4 * OCH];
  __shared__ float biasl[4][64];

  f16x2 e2p[4][5];
#pragma unroll
  for (int nd = 0; nd < 4; ++nd)
#pragma unroll
    for (int dp = 0; dp < 5; ++dp) {
      e2p[nd][dp][0] = (half_t)E[(n0 + nd) * D_EMB + 2 * dp];
      e2p[nd][dp][1] = (half_t)E[(n0 + nd) * D_EMB + 2 * dp + 1];
    }

  if (tid < 256) {
    const int nn = tid >> 6;
    const int o = tid & 63;
    float s = 0.f;
#pragma unroll
    for (int d = 0; d < D_EMB; ++d) s += E[(n0 + nn) * D_EMB + d] * bu[d * COUT + o];
    biasl[nn][o] = s;
  }
  stage_xg4(Cbn, G1n, G2n, S, n0, tid, 512);
  __syncthreads();

  const int fr = lane & 15;
  const int fk = (lane >> 4) * 8;
  const int en = lane & 15;
  const int em = (lane >> 4) * 4;
  const int node = wave & 3;
  const int bh = wave >> 2;
  const int nn = n0 + node;

  f16x8 af[7];
#pragma unroll
  for (int ks = 0; ks < 7; ++ks)
    af[ks] = *(const f16x8*)&S[node * OCH + (bh * 16 + fr) * KILD + ks * 32 + fk];
  __syncthreads();

#pragma unroll
  for (int p = 0; p < 2; ++p) {
    if (p > 0) __syncthreads();
    for (int base = tid * 8; base < OCH; base += 4096) {
      float a[4][8] = {};
#pragma unroll
      for (int dp = 0; dp < 5; ++dp) {
        const unsigned* wrow = WT2 + (size_t)dp * WGT2_R + WROW_G + p * OCH + base;
        uint4 wa = *(const uint4*)wrow;
        uint4 wb = *(const uint4*)(wrow + 4);
        u32h2 c0, c1, c2, c3;
        c0.u = wa.x; c1.u = wa.y; c2.u = wa.z; c3.u = wa.w;
#pragma unroll
        for (int nd = 0; nd < 4; ++nd) {
          a[nd][0] = __builtin_amdgcn_fdot2(c0.h, e2p[nd][dp], a[nd][0], false);
          a[nd][1] = __builtin_amdgcn_fdot2(c1.h, e2p[nd][dp], a[nd][1], false);
          a[nd][2] = __builtin_amdgcn_fdot2(c2.h, e2p[nd][dp], a[nd][2], false);
          a[nd][3] = __builtin_amdgcn_fdot2(c3.h, e2p[nd][dp], a[nd][3], false);
        }
        c0.u = wb.x; c1.u = wb.y; c2.u = wb.z; c3.u = wb.w;
#pragma unroll
        for (int nd = 0; nd < 4; ++nd) {
          a[nd][4] = __builtin_amdgcn_fdot2(c0.h, e2p[nd][dp], a[nd][4], false);
          a[nd][5] = __builtin_amdgcn_fdot2(c1.h, e2p[nd][dp], a[nd][5], false);
          a[nd][6] = __builtin_amdgcn_fdot2(c2.h, e2p[nd][dp], a[nd][6], false);
          a[nd][7] = __builtin_amdgcn_fdot2(c3.h, e2p[nd][dp], a[nd][7], false);
        }
      }
#pragma unroll
      for (int nd = 0; nd < 4; ++nd) {
        f16x8 w0;
#pragma unroll
        for (int e = 0; e < 8; ++e) w0[e] = (half_t)a[nd][e];
        *(f16x8*)&S[nd * OCH + base] = w0;
      }
    }
    __syncthreads();

    f32x4 acc2[2] = {};
#pragma unroll
    for (int ks = 0; ks < 7; ++ks) {
#pragma unroll
      for (int ot = 0; ot < 2; ++ot) {
        const f16x8 b0 = *(const f16x8*)&S[node * OCH + (ot * 16 + fr) * KILD + ks * 32 + fk];
        acc2[ot] = __builtin_amdgcn_mfma_f32_16x16x32_f16(af[ks], b0, acc2[ot], 0, 0, 0);
      }
    }
#pragma unroll
    for (int ot = 0; ot < 2; ++ot) {
      const int o = p * 32 + ot * 16 + en;
      const float bo = biasl[node][o];
#pragma unroll
      for (int r = 0; r < 4; ++r) {
        const int b = bh * 16 + em + r;
        const float hc = fast_tanh(acc2[ot][r] + bo);
        const float hv = H[((size_t)b * N_NODES + nn) * COUT + o];
        const float rr = (float)Rb[(size_t)nn * 2048 + b * COUT + o];
        Out[((size_t)b * N_NODES + nn) * COUT + o] = rr * hv + (1.f - rr) * hc;
      }
    }
  }
}

// ---------------------------------------------------------------------------
extern "C" void kernel_launch(void* const* d_in, const int* in_sizes, int n_in,
                              void* d_out, int out_size, void* d_ws, size_t ws_size,
                              hipStream_t stream) {
  const float* X  = (const float*)d_in[0];
  const float* H  = (const float*)d_in[1];
  const float* E  = (const float*)d_in[2];
  const float* Wg = (const float*)d_in[3];
  const float* bg = (const float*)d_in[4];
  const float* Wu = (const float*)d_in[5];
  const float* bu = (const float*)d_in[6];
  float* out = (float*)d_out;

  const size_t SZ_P = (size_t)N_NODES * N_NODES;
  const size_t SZ_M = (size_t)NPAD * LDT;
  half_t* Pb  = (half_t*)d_ws;
  half_t* Vt  = Pb + SZ_P;
  half_t* Vn  = Vt + SZ_M;
  half_t* G1t = Vn + SZ_M;
  half_t* G1n = G1t + SZ_M;
  half_t* G2n = G1n + SZ_M;
  half_t* Cbt = G2n + SZ_M;
  half_t* Cbn = Cbt + SZ_M;
  half_t* Rb  = Cbn + SZ_M;
  unsigned* WT2 = (unsigned*)(Rb + (size_t)BATCH * N_NODES * COUT);

  const dim3 gg(17, 32);       // full-K GEMM grid
  const dim3 gt(33, 64);       // 64x64 tile grid over 2112 cols x 4096 nodes

  // 1. adjacency + inputs + packed pool
  k_softmax_p<<<N_NODES, 256, 0, stream>>>(E, Pb);
  k_build_v0<<<gt, 256, 0, stream>>>(X, H, Vt, Vn, Cbn);
  k_wgt2<<<(WGT2_R + 255) / 256, 256, 0, stream>>>(Wg, Wu, WT2);

  // 2. gate propagation + transform
  k_gemm_f16<<<gg, 512, 0, stream>>>(Pb, Vt, G1n, G1t);
  k_gemm_f16<<<gg, 512, 0, stream>>>(Pb, G1t, G2n, nullptr);
  k_gate_t<<<N_NODES / 4, 512, 0, stream>>>(Vn, G1n, G2n, WT2, E, bg, H, Cbn, Rb);
  k_tr<<<gt, 256, 0, stream>>>(Cbn, Cbt);

  // 3. update propagation + transform + output
  k_gemm_f16<<<gg, 512, 0, stream>>>(Pb, Cbt, G1n, G1t);
  k_gemm_f16<<<gg, 512, 0, stream>>>(Pb, G1t, G2n, nullptr);
  k_update_t<<<N_NODES / 4, 512, 0, stream>>>(Cbn, G1n, G2n, WT2, E, bu, H, Rb, out);
}